// Round 11
// baseline (198.566 us; speedup 1.0000x reference)
//
#include <hip/hip_runtime.h>
#include <math.h>

// Problem constants (fixed by reference setup_inputs)
#define S      2048
#define DK     64
#define NBH    32            // B*H
#define QBLK   128           // q rows per block (4 q-groups x 32 rows)
#define NQB    (S / QBLK)    // 16 q-tiles per bh
#define NBLK   (NBH * NQB)   // 512 blocks = 2/CU (single generation)
#define NTHR   512
#define KHALF  1024          // k rows per wave (half range)
#define KPH    64            // k rows staged per phase per stream (8 KB bf16)
#define NPH    (KHALF / KPH) // 16 phases
#define NST    (KPH / 16)    // 4 MFMA steps per phase

typedef __bf16 bf16x8 __attribute__((ext_vector_type(8)));
typedef float  f32x4  __attribute__((ext_vector_type(4)));
typedef float  f32x8  __attribute__((ext_vector_type(8)));

#if __has_builtin(__builtin_amdgcn_exp2f)
#define EXP2F(x) __builtin_amdgcn_exp2f(x)
#else
#define EXP2F(x) exp2f(x)
#endif

__device__ __forceinline__ float gelu_exact(float x) {
    return 0.5f * x * (1.0f + erff(x * 0.70710678118654752f));
}

// ---------------------------------------------------------------------------
// v10 (re-run; r10 was an infra failure — kernel never executed).
// FAT WAVES (32 q-rows) x 4 WAVES/SIMD x VGPR=128, slim registers.
// Ledger r1-r9: dur ~= stats-VALU-work (~17us) / VALUBusy.  r8 (best, 84us):
// fat waves at 2 waves/SIMD, VALUBusy 20.5%, ~2 steps in flight at the
// 128-VGPR ceiling.  r9 (split-K, 1024thr): compiler chose VGPR=64 -> ILP
// strangled (VALUBusy 11%) -- the occupancy experiment never ran.  v10 runs
// it properly:
//  * __launch_bounds__(512,4): 4 waves/EU -> 2 blocks/CU, VGPR cap = 128
//    exactly (no compiler discretion).
//  * Grid (32 bh, 16 qt) = 512 blocks = 2/CU = 16 waves/CU; wave w =
//    q-group (w>>1, 32 rows) x k-half (w&1, 1024 rows) -- r9's validated
//    in-block split-K combine.
//  * Register diet vs r8: staging 16 regs (64-row phases, was 32), sm[8] ->
//    2 tree chains; persistent ~58 regs -> ~3 steps in flight at cap 128.
//  * Two K streams, each double-buffered 8 KB, T2 XOR-swizzle (0 conflicts
//    since r7), T14 issue-early/write-late, ONE raw s_barrier per phase,
//    vmcnt never drained at a barrier.  Race-free: the WRITE for phase p+1
//    is ordered after the barrier that retired phase p-1's readers.
// Stats in log2 domain (Q pre-scaled by (1/8)*log2e): per q-row m=max s',
// Z=sum 2^s', Z2=sum 2^2s'; block sm = sum s' (2 chains/thread).  K-halves
// combine in-block via a 4 KB LDS table (Z/Z2 add, m fmax), then
// var=(Z2/Z^2-1/n)/(n-1); sum/max restored by *ln2.  |s'|<~9: no overflow.
// Last block (atomic counter) runs the 3->64->64->1 GELU MLP head.
// ---------------------------------------------------------------------------
__global__ __launch_bounds__(NTHR, 4) void fused_attn_stats_mlp(
    const float* __restrict__ Q, const float* __restrict__ K,
    const float* __restrict__ W1, const float* __restrict__ b1,
    const float* __restrict__ W2, const float* __restrict__ b2,
    const float* __restrict__ W3, const float* __restrict__ b3,
    float* __restrict__ ws, float* __restrict__ out)
{
    // [ kh0 par0 8KB | kh0 par1 8KB | kh1 par0 8KB | kh1 par1 8KB ] = 32 KB
    __shared__ __align__(16) unsigned char smem[32 * 1024];

    const int t    = threadIdx.x;
    const int lane = t & 63;
    const int w    = t >> 6;        // wave 0..7
    const int qg   = w >> 1;        // q-group 0..3 -> rows [qg*32, +32)
    const int kh   = w & 1;         // k-half 0/1 -> rows [kh*1024, +1024)
    const int lrow = lane & 15;     // fragment row index
    const int lq   = lane >> 4;     // quad: d = lq*8 + j
    const int bh   = blockIdx.x;
    const int qb   = blockIdx.y;

    // ---- Q loads first (vmcnt in-order: A-cvt waits only on Q) ----
    const float SC = 0.18033688011112042592f;      // (1/sqrt(64)) * log2(e)
    const float* qrow = Q + ((size_t)bh * S + (size_t)qb * QBLK + qg * 32 + lrow) * DK;
    f32x8 qa = *(const f32x8*)(qrow + lq * 8);
    f32x8 qv = *(const f32x8*)(qrow + 32 + lq * 8);
    f32x8 qc = *(const f32x8*)(qrow + 16 * DK + lq * 8);
    f32x8 qd = *(const f32x8*)(qrow + 16 * DK + 32 + lq * 8);

    // ---- staging: 256 threads per stream; thread owns 16 floats/phase ----
    const int n    = t & 255;       // id within the stream's staging set
    const int sidx = t >> 8;        // which k-half this thread stages
    const int srow = n >> 2;        // buffer-local row 0..63
    const int g0   = (n & 3) * 2;   // first 16B group (of 8 per row)
    const int sx   = srow & 7;      // swizzle term
    const int adrA = srow * 128 + ((g0 ^ sx) << 4);
    const int adrB = srow * 128 + (((g0 + 1) ^ sx) << 4);
    const float* gK = K + (size_t)bh * S * DK + (size_t)sidx * KHALF * DK
                        + (size_t)srow * DK + (n & 3) * 16;
    char* myBuf = (char*)smem + sidx * 16384;

    f32x4 s0, s1, s2, s3;           // 16 persistent staging VGPRs
#define ISSUE(p) { const float* _gp = gK + (size_t)(p) * (KPH * DK);       \
        s0 = *(const f32x4*)(_gp);      s1 = *(const f32x4*)(_gp + 4);     \
        s2 = *(const f32x4*)(_gp + 8);  s3 = *(const f32x4*)(_gp + 12); }

#define WRITE(par) { char* _d = myBuf + (par) * 8192;                      \
        f32x8 _a = __builtin_shufflevector(s0, s1, 0, 1, 2, 3, 4, 5, 6, 7);\
        f32x8 _b = __builtin_shufflevector(s2, s3, 0, 1, 2, 3, 4, 5, 6, 7);\
        *(bf16x8*)(_d + adrA) = __builtin_convertvector(_a, bf16x8);       \
        *(bf16x8*)(_d + adrB) = __builtin_convertvector(_b, bf16x8); }

#define PIPE_BAR() {                                                       \
        asm volatile("s_waitcnt lgkmcnt(0)" ::: "memory");                 \
        __builtin_amdgcn_s_barrier();                                      \
        asm volatile("" ::: "memory"); }

    // ---- prologue ----
    ISSUE(0);
    const bf16x8 a0_lo = __builtin_convertvector(qa * SC, bf16x8);
    const bf16x8 a0_hi = __builtin_convertvector(qv * SC, bf16x8);
    const bf16x8 a1_lo = __builtin_convertvector(qc * SC, bf16x8);
    const bf16x8 a1_hi = __builtin_convertvector(qd * SC, bf16x8);
    WRITE(0);                       // waits phase-0 vmcnt only
    __syncthreads();                // both streams' parity-0 buffers visible

    float m[8], Zs[8], Z2[8];       // u = f*4+i -> row qg*32 + f*16 + lq*4 + i
#pragma unroll
    for (int u = 0; u < 8; ++u) { m[u] = -INFINITY; Zs[u] = 0.f; Z2[u] = 0.f; }
    float sm0 = 0.f, sm1 = 0.f;     // block-sum of s' (two tree chains)

    const int obase = lrow * 128 + ((lq ^ (lrow & 7)) << 4);
    const char* rdBase = (const char*)smem + kh * 16384;

    for (int p = 0; p < NPH; ++p) {
        if (p + 1 < NPH) ISSUE(p + 1);          // in flight across the phase
        const char* HB = rdBase + (p & 1) * 8192;
#pragma unroll
        for (int j = 0; j < NST; ++j) {
            const int off = j * 2048 + obase;
            const bf16x8 b_lo = *(const bf16x8*)(HB + off);
            const bf16x8 b_hi = *(const bf16x8*)(HB + (off ^ 64));
            f32x4 ac0 = {0.f, 0.f, 0.f, 0.f};
            f32x4 ac1 = {0.f, 0.f, 0.f, 0.f};
            ac0 = __builtin_amdgcn_mfma_f32_16x16x32_bf16(a0_lo, b_lo, ac0, 0, 0, 0);
            ac0 = __builtin_amdgcn_mfma_f32_16x16x32_bf16(a0_hi, b_hi, ac0, 0, 0, 0);
            ac1 = __builtin_amdgcn_mfma_f32_16x16x32_bf16(a1_lo, b_lo, ac1, 0, 0, 0);
            ac1 = __builtin_amdgcn_mfma_f32_16x16x32_bf16(a1_hi, b_hi, ac1, 0, 0, 0);
#pragma unroll
            for (int i = 0; i < 4; ++i) {
                const float v0 = ac0[i], v1 = ac1[i];
                const float p0 = EXP2F(v0), p1 = EXP2F(v1);
                m[i]      = fmaxf(m[i], v0);      m[4 + i]  = fmaxf(m[4 + i], v1);
                Zs[i]    += p0;                   Zs[4 + i] += p1;
                Z2[i]     = fmaf(p0, p0, Z2[i]);
                Z2[4 + i] = fmaf(p1, p1, Z2[4 + i]);
            }
            sm0 += (ac0[0] + ac0[1]) + (ac0[2] + ac0[3]);
            sm1 += (ac1[0] + ac1[1]) + (ac1[2] + ac1[3]);
        }
        if (p + 1 < NPH) {
            WRITE((p + 1) & 1);                 // vmcnt wait: one phase old
            PIPE_BAR();                         // buffer ready; vmcnt NOT drained
        }
    }
    __syncthreads();                            // all compute done; LDS reusable

    // ---- reduce m/Z/Z2 across the 16 col-lanes, publish per-row partials --
#pragma unroll
    for (int off = 1; off < 16; off <<= 1) {
#pragma unroll
        for (int u = 0; u < 8; ++u) {
            m[u]   = fmaxf(m[u], __shfl_xor(m[u], off, 64));
            Zs[u] += __shfl_xor(Zs[u], off, 64);
            Z2[u] += __shfl_xor(Z2[u], off, 64);
        }
    }
    float4* part  = (float4*)smem;              // part[kh*128 + row], 4 KB
    float*  red   = (float*)(smem + 4096);      // 3 floats
    int*    lastF = (int*)(smem + 4112);
    if (lrow == 0) {
#pragma unroll
        for (int u = 0; u < 8; ++u) {
            const int R = qg * 32 + (u >> 2) * 16 + lq * 4 + (u & 3);
            part[kh * 128 + R] = make_float4(m[u], Zs[u], Z2[u], 0.f);
        }
    }
    if (t < 3) red[t] = 0.0f;

    // block-sum of s' (every lane holds disjoint (q,k) partial sums)
    float smv = sm0 + sm1;
#pragma unroll
    for (int off = 1; off < 64; off <<= 1) smv += __shfl_xor(smv, off, 64);
    __syncthreads();
    if (lane == 0) atomicAdd(&red[0], smv);

    // ---- combine k-halves per row; reduce pmax/pvar over 128 rows ----
    {
        float pmax = 0.f, pvar = 0.f;
        if (w < 2) {                            // threads 0..127 = rows 0..127
            const float4 A = part[t];
            const float4 B = part[128 + t];
            const float Z  = A.y + B.y;
            const float iz = 1.0f / Z;
            pmax = fmaxf(A.x, B.x);
            pvar = ((A.z + B.z) * iz * iz - (1.0f / 2048.0f)) * (1.0f / 2047.0f);
#pragma unroll
            for (int off = 1; off < 64; off <<= 1) {
                pmax += __shfl_xor(pmax, off, 64);
                pvar += __shfl_xor(pvar, off, 64);
            }
            if (lane == 0) {
                atomicAdd(&red[1], pmax);
                atomicAdd(&red[2], pvar);
            }
        }
    }
    __syncthreads();
    if (t == 0) {
        const float LN2 = 0.69314718055994530942f;
        atomicAdd(&ws[bh * 3 + 0], red[0] * LN2);   // back to natural-log domain
        atomicAdd(&ws[bh * 3 + 1], red[1] * LN2);
        atomicAdd(&ws[bh * 3 + 2], red[2]);
        __threadfence();
        const int old = atomicAdd((int*)(ws + 96), 1);
        *lastF = (old == NBLK - 1);
    }
    __syncthreads();
    if (!*lastF) return;

    // =========================== MLP head (last block) ======================
    float* H1    = (float*)(smem + 4160);   // 32*65 floats
    float* featL = H1 + 32 * 65;            // 96 floats
    float* logtL = featL + 96;              // 32 floats   (< 32 KB total)

    if (t < 96)               featL[t] = atomicAdd(&ws[t], 0.0f); // coherent read
    if (t >= 96 && t < 128)   logtL[t - 96] = 0.0f;
    __syncthreads();

    if (t < 64) {
        const float w1a = W1[t], w1b = W1[64 + t], w1c = W1[128 + t], bb1 = b1[t];
        for (int b = 0; b < 32; ++b) {
            const float f0 = featL[b * 3 + 0] * (1.0f / ((float)S * (float)S));
            const float f1 = featL[b * 3 + 1] * (1.0f / (float)S);
            const float f2 = featL[b * 3 + 2] * (1.0f / (float)S);
            H1[b * 65 + t] = gelu_exact(f0 * w1a + f1 * w1b + f2 * w1c + bb1);
        }
    }
    __syncthreads();
    {
        // 512 threads: 16 threads per bh, 4 hidden-2 units each
        const int b = t >> 4, jb = (t & 15) * 4;
        float a0 = 0.f, a1 = 0.f, a2 = 0.f, a3 = 0.f;
        for (int k = 0; k < 64; ++k) {
            const float hk = H1[b * 65 + k];
            const float4 wa = *(const float4*)&W2[k * 64 + jb];
            a0 += hk * wa.x; a1 += hk * wa.y; a2 += hk * wa.z; a3 += hk * wa.w;
        }
        const float partl = gelu_exact(a0 + b2[jb + 0]) * W3[jb + 0]
                          + gelu_exact(a1 + b2[jb + 1]) * W3[jb + 1]
                          + gelu_exact(a2 + b2[jb + 2]) * W3[jb + 2]
                          + gelu_exact(a3 + b2[jb + 3]) * W3[jb + 3];
        atomicAdd(&logtL[b], partl);
    }
    __syncthreads();
    if (t < 32) {
        float lt = logtL[t] + b3[0];
        lt = fminf(fmaxf(lt, -2.3025850929940457f), 2.3025850929940457f);
        out[t] = expf(lt);
    }
}

// ---------------------------------------------------------------------------
extern "C" void kernel_launch(void* const* d_in, const int* in_sizes, int n_in,
                              void* d_out, int out_size, void* d_ws, size_t ws_size,
                              hipStream_t stream)
{
    const float* Q  = (const float*)d_in[0];
    const float* K  = (const float*)d_in[1];
    const float* W1 = (const float*)d_in[2];
    const float* b1 = (const float*)d_in[3];
    const float* W2 = (const float*)d_in[4];
    const float* b2 = (const float*)d_in[5];
    const float* W3 = (const float*)d_in[6];
    const float* b3 = (const float*)d_in[7];
    float* out = (float*)d_out;
    float* ws  = (float*)d_ws;

    // zero the 96 stat accumulators + the int block counter at ws[96]
    hipMemsetAsync(ws, 0, 512, stream);

    dim3 grid(NBH, NQB);   // bh fastest -> each bh's K pinned to one XCD L2
    fused_attn_stats_mlp<<<grid, NTHR, 0, stream>>>(Q, K, W1, b1, W2, b2, W3, b3, ws, out);
}

// Round 12
// 165.324 us; speedup vs baseline: 1.2011x; 1.2011x over previous
//
#include <hip/hip_runtime.h>
#include <math.h>

// Problem constants (fixed by reference setup_inputs)
#define S      2048
#define DK     64
#define NBH    32            // B*H
#define QW     64            // q rows per WAVE (4 A-fragment pairs)
#define QBLK   256           // q rows per block (4 q-groups x 64)
#define NQB    (S / QBLK)    // 8 q-tiles per bh
#define NBLK   (NBH * NQB)   // 256 blocks = 1/CU
#define NTHR   512
#define KHALF  1024          // k rows per wave (half range)
#define KPH    64            // k rows staged per phase per stream (8 KB bf16)
#define NPH    (KHALF / KPH) // 16 phases
#define NST    (KPH / 16)    // 4 MFMA steps per phase

typedef __bf16 bf16x8 __attribute__((ext_vector_type(8)));
typedef float  f32x4  __attribute__((ext_vector_type(4)));
typedef float  f32x8  __attribute__((ext_vector_type(8)));

#if __has_builtin(__builtin_amdgcn_exp2f)
#define EXP2F(x) __builtin_amdgcn_exp2f(x)
#else
#define EXP2F(x) exp2f(x)
#endif

__device__ __forceinline__ float gelu_exact(float x) {
    return 0.5f * x * (1.0f + erff(x * 0.70710678118654752f));
}

// ---------------------------------------------------------------------------
// v12: 64-Q-ROW WAVES (step-count halving) x in-block split-K.
// Ledger r5/r7/r8/r11 normalized: per-wave per-step latency ~1600-1900 cyc
// in EVERY structure; wall = steps/SIMD x latency / TLP.  TLP is compiler-
// limited (r9/r11: allocator shrinks VGPR to 64 when live state is small,
// killing ILP).  Remaining lever = fewer steps: r8's 16->32 q-rows/wave was
// -19%; v12 goes 32->64 (4 A-frag pairs), halving total wave-steps vs r8
// (262k->131k) while per-step issue (~300cyc: 8 MFMA + 16 exp + ~64 VALU
// off ONE ds_read pair) stays under the step latency.  Persistent regs
// ~104 (A 32 + stats 52 + staging 16) -> compiler cannot shrink below
// ~110; plain __launch_bounds__(512) like r8 (the only config that held
// VGPR=128).
// Geometry: 512 thr = 8 waves; wave w = q-group (w>>1, 64 rows) x k-half
// (w&1, 1024 rows) -- r9/r11-validated in-block split-K combine.  Grid
// (32 bh, 8 qb) = 256 blocks = 1/CU, bh-major XCD-pinned K (FETCH 16.5MB).
// K staging: 2 streams (one per k-half), KPH=64 double-buffered 8KB, T2
// XOR-swizzle (0 conflicts since r7), T14 issue-early/write-late, ONE raw
// s_barrier per phase, vmcnt never drained.  Race-free: WRITE for phase
// p+1 is ordered after the barrier that retired phase p-1's readers.
// Stats in log2 domain (Q pre-scaled by (1/8)*log2e): per q-row m=max s',
// Z=sum 2^s', Z2=sum 2^2s'; block sm = sum s' (4 chains).  K-halves
// combine in-block via an 8 KB LDS table (Z/Z2 add, m fmax), then
// var=(Z2/Z^2-1/n)/(n-1); sum/max restored by *ln2.  |s'|<~9: no overflow.
// Last block (atomic counter) runs the 3->64->64->1 GELU MLP head.
// ---------------------------------------------------------------------------
__global__ __launch_bounds__(NTHR) void fused_attn_stats_mlp(
    const float* __restrict__ Q, const float* __restrict__ K,
    const float* __restrict__ W1, const float* __restrict__ b1,
    const float* __restrict__ W2, const float* __restrict__ b2,
    const float* __restrict__ W3, const float* __restrict__ b3,
    float* __restrict__ ws, float* __restrict__ out)
{
    // [ kh0 par0 8KB | kh0 par1 8KB | kh1 par0 8KB | kh1 par1 8KB ] = 32 KB
    __shared__ __align__(16) unsigned char smem[32 * 1024];

    const int t    = threadIdx.x;
    const int lane = t & 63;
    const int w    = t >> 6;        // wave 0..7
    const int qg   = w >> 1;        // q-group 0..3 -> rows [qg*64, +64)
    const int kh   = w & 1;         // k-half 0/1 -> rows [kh*1024, +1024)
    const int lrow = lane & 15;     // fragment row index
    const int lq   = lane >> 4;     // quad: d = lq*8 + j
    const int bh   = blockIdx.x;
    const int qb   = blockIdx.y;

    // ---- A fragments: 4 pairs (64 q-rows), scaled by (1/8)*log2(e) ----
    const float SC = 0.18033688011112042592f;
    const float* qbase = Q + ((size_t)bh * S + (size_t)qb * QBLK + qg * QW + lrow) * DK;
    bf16x8 alo[4], ahi[4];
#pragma unroll
    for (int f = 0; f < 4; ++f) {
        f32x8 x = *(const f32x8*)(qbase + f * 16 * DK + lq * 8);
        f32x8 y = *(const f32x8*)(qbase + f * 16 * DK + 32 + lq * 8);
        alo[f] = __builtin_convertvector(x * SC, bf16x8);
        ahi[f] = __builtin_convertvector(y * SC, bf16x8);
    }

    // ---- staging: 256 threads per stream; thread owns 16 floats/phase ----
    const int n    = t & 255;       // id within the stream's staging set
    const int sidx = t >> 8;        // which k-half this thread stages
    const int srow = n >> 2;        // buffer-local row 0..63
    const int g0   = (n & 3) * 2;   // first 16B group (of 8 per row)
    const int sx   = srow & 7;      // swizzle term
    const int adrA = srow * 128 + ((g0 ^ sx) << 4);
    const int adrB = srow * 128 + (((g0 + 1) ^ sx) << 4);
    const float* gK = K + (size_t)bh * S * DK + (size_t)sidx * KHALF * DK
                        + (size_t)srow * DK + (n & 3) * 16;
    char* myBuf = (char*)smem + sidx * 16384;

    f32x4 s0, s1, s2, s3;           // 16 persistent staging VGPRs
#define ISSUE(p) { const float* _gp = gK + (size_t)(p) * (KPH * DK);       \
        s0 = *(const f32x4*)(_gp);      s1 = *(const f32x4*)(_gp + 4);     \
        s2 = *(const f32x4*)(_gp + 8);  s3 = *(const f32x4*)(_gp + 12); }

#define WRITE(par) { char* _d = myBuf + (par) * 8192;                      \
        f32x8 _a = __builtin_shufflevector(s0, s1, 0, 1, 2, 3, 4, 5, 6, 7);\
        f32x8 _b = __builtin_shufflevector(s2, s3, 0, 1, 2, 3, 4, 5, 6, 7);\
        *(bf16x8*)(_d + adrA) = __builtin_convertvector(_a, bf16x8);       \
        *(bf16x8*)(_d + adrB) = __builtin_convertvector(_b, bf16x8); }

#define PIPE_BAR() {                                                       \
        asm volatile("s_waitcnt lgkmcnt(0)" ::: "memory");                 \
        __builtin_amdgcn_s_barrier();                                      \
        asm volatile("" ::: "memory"); }

    // ---- prologue ----
    ISSUE(0);
    WRITE(0);                       // waits phase-0 vmcnt (and Q) only
    __syncthreads();                // both streams' parity-0 buffers visible

    float m[16], Zs[16], Z2[16];    // u = f*4+i -> row qg*64 + f*16 + lq*4 + i
#pragma unroll
    for (int u = 0; u < 16; ++u) { m[u] = -INFINITY; Zs[u] = 0.f; Z2[u] = 0.f; }
    float sm[4];                    // block-sum of s' (one chain per A-pair)
#pragma unroll
    for (int f = 0; f < 4; ++f) sm[f] = 0.f;

    const int obase = lrow * 128 + ((lq ^ (lrow & 7)) << 4);
    const char* rdBase = (const char*)smem + kh * 16384;

    for (int p = 0; p < NPH; ++p) {
        if (p + 1 < NPH) ISSUE(p + 1);          // in flight across the phase
        const char* HB = rdBase + (p & 1) * 8192;
#pragma unroll
        for (int j = 0; j < NST; ++j) {
            const int off = j * 2048 + obase;
            const bf16x8 b_lo = *(const bf16x8*)(HB + off);
            const bf16x8 b_hi = *(const bf16x8*)(HB + (off ^ 64));
            f32x4 ac[4];
#pragma unroll
            for (int f = 0; f < 4; ++f) {
                f32x4 a = {0.f, 0.f, 0.f, 0.f};
                a = __builtin_amdgcn_mfma_f32_16x16x32_bf16(alo[f], b_lo, a, 0, 0, 0);
                a = __builtin_amdgcn_mfma_f32_16x16x32_bf16(ahi[f], b_hi, a, 0, 0, 0);
                ac[f] = a;
            }
#pragma unroll
            for (int f = 0; f < 4; ++f) {
#pragma unroll
                for (int i = 0; i < 4; ++i) {
                    const float v = ac[f][i];
                    const float e = EXP2F(v);
                    m[f * 4 + i]  = fmaxf(m[f * 4 + i], v);
                    Zs[f * 4 + i] += e;
                    Z2[f * 4 + i]  = fmaf(e, e, Z2[f * 4 + i]);
                }
                sm[f] += (ac[f][0] + ac[f][1]) + (ac[f][2] + ac[f][3]);
            }
        }
        if (p + 1 < NPH) {
            WRITE((p + 1) & 1);                 // vmcnt wait: one phase old
            PIPE_BAR();                         // buffer ready; vmcnt NOT drained
        }
    }
    __syncthreads();                            // all compute done; LDS reusable

    // ---- reduce m/Z/Z2 across the 16 col-lanes, publish per-row partials --
#pragma unroll
    for (int off = 1; off < 16; off <<= 1) {
#pragma unroll
        for (int u = 0; u < 16; ++u) {
            m[u]   = fmaxf(m[u], __shfl_xor(m[u], off, 64));
            Zs[u] += __shfl_xor(Zs[u], off, 64);
            Z2[u] += __shfl_xor(Z2[u], off, 64);
        }
    }
    float4* part  = (float4*)smem;              // part[kh*256 + row], 8 KB
    float*  red   = (float*)(smem + 8192);      // 3 floats
    int*    lastF = (int*)(smem + 8208);
    if (lrow == 0) {
#pragma unroll
        for (int u = 0; u < 16; ++u) {
            const int R = qg * QW + (u >> 2) * 16 + lq * 4 + (u & 3);
            part[kh * 256 + R] = make_float4(m[u], Zs[u], Z2[u], 0.f);
        }
    }
    if (t < 3) red[t] = 0.0f;

    // block-sum of s' (every lane holds disjoint (q,k) partial sums)
    float smv = (sm[0] + sm[1]) + (sm[2] + sm[3]);
#pragma unroll
    for (int off = 1; off < 64; off <<= 1) smv += __shfl_xor(smv, off, 64);
    __syncthreads();
    if (lane == 0) atomicAdd(&red[0], smv);

    // ---- combine k-halves per row; reduce pmax/pvar over 256 rows ----
    {
        float pmax = 0.f, pvar = 0.f;
        if (w < 4) {                            // threads 0..255 = rows 0..255
            const float4 A = part[t];
            const float4 B = part[256 + t];
            const float Z  = A.y + B.y;
            const float iz = 1.0f / Z;
            pmax = fmaxf(A.x, B.x);
            pvar = ((A.z + B.z) * iz * iz - (1.0f / 2048.0f)) * (1.0f / 2047.0f);
#pragma unroll
            for (int off = 1; off < 64; off <<= 1) {
                pmax += __shfl_xor(pmax, off, 64);
                pvar += __shfl_xor(pvar, off, 64);
            }
            if (lane == 0) {
                atomicAdd(&red[1], pmax);
                atomicAdd(&red[2], pvar);
            }
        }
    }
    __syncthreads();
    if (t == 0) {
        const float LN2 = 0.69314718055994530942f;
        atomicAdd(&ws[bh * 3 + 0], red[0] * LN2);   // back to natural-log domain
        atomicAdd(&ws[bh * 3 + 1], red[1] * LN2);
        atomicAdd(&ws[bh * 3 + 2], red[2]);
        __threadfence();
        const int old = atomicAdd((int*)(ws + 96), 1);
        *lastF = (old == NBLK - 1);
    }
    __syncthreads();
    if (!*lastF) return;

    // =========================== MLP head (last block) ======================
    float* H1    = (float*)(smem + 8256);   // 32*65 floats
    float* featL = H1 + 32 * 65;            // 96 floats
    float* logtL = featL + 96;              // 32 floats   (< 32 KB total)

    if (t < 96)               featL[t] = atomicAdd(&ws[t], 0.0f); // coherent read
    if (t >= 96 && t < 128)   logtL[t - 96] = 0.0f;
    __syncthreads();

    if (t < 64) {
        const float w1a = W1[t], w1b = W1[64 + t], w1c = W1[128 + t], bb1 = b1[t];
        for (int b = 0; b < 32; ++b) {
            const float f0 = featL[b * 3 + 0] * (1.0f / ((float)S * (float)S));
            const float f1 = featL[b * 3 + 1] * (1.0f / (float)S);
            const float f2 = featL[b * 3 + 2] * (1.0f / (float)S);
            H1[b * 65 + t] = gelu_exact(f0 * w1a + f1 * w1b + f2 * w1c + bb1);
        }
    }
    __syncthreads();
    {
        // 512 threads: 16 threads per bh, 4 hidden-2 units each
        const int b = t >> 4, jb = (t & 15) * 4;
        float a0 = 0.f, a1 = 0.f, a2 = 0.f, a3 = 0.f;
        for (int k = 0; k < 64; ++k) {
            const float hk = H1[b * 65 + k];
            const float4 wa = *(const float4*)&W2[k * 64 + jb];
            a0 += hk * wa.x; a1 += hk * wa.y; a2 += hk * wa.z; a3 += hk * wa.w;
        }
        const float partl = gelu_exact(a0 + b2[jb + 0]) * W3[jb + 0]
                          + gelu_exact(a1 + b2[jb + 1]) * W3[jb + 1]
                          + gelu_exact(a2 + b2[jb + 2]) * W3[jb + 2]
                          + gelu_exact(a3 + b2[jb + 3]) * W3[jb + 3];
        atomicAdd(&logtL[b], partl);
    }
    __syncthreads();
    if (t < 32) {
        float lt = logtL[t] + b3[0];
        lt = fminf(fmaxf(lt, -2.3025850929940457f), 2.3025850929940457f);
        out[t] = expf(lt);
    }
}

// ---------------------------------------------------------------------------
extern "C" void kernel_launch(void* const* d_in, const int* in_sizes, int n_in,
                              void* d_out, int out_size, void* d_ws, size_t ws_size,
                              hipStream_t stream)
{
    const float* Q  = (const float*)d_in[0];
    const float* K  = (const float*)d_in[1];
    const float* W1 = (const float*)d_in[2];
    const float* b1 = (const float*)d_in[3];
    const float* W2 = (const float*)d_in[4];
    const float* b2 = (const float*)d_in[5];
    const float* W3 = (const float*)d_in[6];
    const float* b3 = (const float*)d_in[7];
    float* out = (float*)d_out;
    float* ws  = (float*)d_ws;

    // zero the 96 stat accumulators + the int block counter at ws[96]
    hipMemsetAsync(ws, 0, 512, stream);

    dim3 grid(NBH, NQB);   // bh fastest -> each bh's K pinned to one XCD L2
    fused_attn_stats_mlp<<<grid, NTHR, 0, stream>>>(Q, K, W1, b1, W2, b2, W3, b3, ws, out);
}